// Round 11
// baseline (79.820 us; speedup 1.0000x reference)
//
#include <hip/hip_runtime.h>
#include <hip/hip_bf16.h>

#define NB 4
#define N_NODES 100000
#define E_EDGES 160000
#define EA_E 80000
#define HID 128
#define ED 16

#define TILE_M 128
#define THREADS 256
#define XPAD 40   // xs row length in ushort (32 used) -> 80B stride

typedef __attribute__((ext_vector_type(8))) short bf16x8;
typedef __attribute__((ext_vector_type(4))) float f32x4;
typedef __attribute__((ext_vector_type(8))) unsigned short u16x8;

__device__ __forceinline__ unsigned short f2bf(float f) {
    union { __hip_bfloat16 b; unsigned short u; } v;
    v.b = __float2bfloat16(f);   // RTNE
    return v.u;
}

// ---- pre-kernel: W1 (fp32 [272][128]) -> bf16 fragments in d_ws ----
// W1F[((c*8 + ni)*64 + lane)*8 + j]; n = ni*16 + (lane&15), k = c*32 + (lane>>4)*8 + j
__global__ void prep_w1(const float* __restrict__ W1, unsigned short* __restrict__ W1F) {
    const int cb   = blockIdx.x;      // 0..71 = c*8 + ni
    const int c    = cb >> 3;
    const int ni   = cb & 7;
    const int lane = threadIdx.x;     // 0..63
    const int fr   = lane & 15;
    const int fq   = lane >> 4;
    const int n    = ni * 16 + fr;
    u16x8 v;
    #pragma unroll
    for (int j = 0; j < 8; ++j) {
        int k = c * 32 + fq * 8 + j;
        float f = (k < 272) ? W1[(size_t)k * HID + n] : 0.f;
        v[j] = f2bf(f);
    }
    *reinterpret_cast<u16x8*>(W1F + ((size_t)(cb * 64 + lane)) * 8) = v;
}

__global__ __launch_bounds__(THREADS, 3) void actor_head_mfma(
    const float* __restrict__ h,            // [B][N][128]
    const int*   __restrict__ edge_index,   // [2][E]
    const float* __restrict__ edge_attr,    // [B][E][16]
    const int*   __restrict__ etype,        // [EA]
    const unsigned short* __restrict__ W1F, // bf16 fragment-ordered W1
    const float* __restrict__ b1,           // [128]
    const float* __restrict__ W2,           // [128][2]
    const float* __restrict__ b2,           // [2]
    float*       __restrict__ out)          // [B][EA/2][2]
{
    // xs is WAVE-PRIVATE by construction: wave w (t in [64w,64w+64)) writes
    // rows sm = t>>1 in [32w,32w+32) and reads exactly rows wm+fr, wm+16+fr
    // with wm = 32w. Same-wave DS ops are in-order -> no block barriers needed
    // after the initial sel sync. B never touches LDS: each lane's fragment
    // is the 16B it loads itself, register double-buffered (bwA/bwB).
    __shared__ unsigned short xs[2][TILE_M][XPAD];
    __shared__ int sel[3][TILE_M];

    const int b  = blockIdx.y;
    const int e0 = blockIdx.x * TILE_M;
    const int t  = threadIdx.x;

    if (t < TILE_M) {
        int ei = etype[e0 + t];
        sel[2][t] = ei;
        sel[0][t] = edge_index[ei];
        sel[1][t] = edge_index[E_EDGES + ei];
    }

    const int lane = t & 63;
    const int wid  = t >> 6;          // 0..3
    const int wm   = wid * 32;        // wave owns rows wm..wm+31, all 128 cols
    const int fr   = lane & 15;
    const int fq   = lane >> 4;

    // staging roles: 2 threads per x row, 16 floats each
    const int sm = t >> 1;
    const int sh = t & 1;

    f32x4 tv[4];
    bf16x8 bwA[8], bwB[8];
    f32x4 acc[2][8];
    #pragma unroll
    for (int i = 0; i < 2; ++i)
        #pragma unroll
        for (int j = 0; j < 8; ++j) acc[i][j] = (f32x4){0.f, 0.f, 0.f, 0.f};

    __syncthreads();   // the ONLY block barrier: sel visible to all waves

    const float* hr = h + ((size_t)b * N_NODES + sel[0][sm]) * HID + sh * 16;
    const float* hs = h + ((size_t)b * N_NODES + sel[1][sm]) * HID + sh * 16;
    const float* ea = edge_attr + ((size_t)b * E_EDGES + sel[2][sm]) * ED;

#define GATHER(cn) do { if ((cn) <= 8) { \
    if ((cn) < 8) { \
        const float* q = (((cn) < 4) ? hr : hs) + ((cn) & 3) * 32; \
        tv[0] = *reinterpret_cast<const f32x4*>(q); \
        tv[1] = *reinterpret_cast<const f32x4*>(q + 4); \
        tv[2] = *reinterpret_cast<const f32x4*>(q + 8); \
        tv[3] = *reinterpret_cast<const f32x4*>(q + 12); \
    } else if (sh == 0) { \
        tv[0] = *reinterpret_cast<const f32x4*>(ea); \
        tv[1] = *reinterpret_cast<const f32x4*>(ea + 4); \
        tv[2] = *reinterpret_cast<const f32x4*>(ea + 8); \
        tv[3] = *reinterpret_cast<const f32x4*>(ea + 12); \
    } else { \
        tv[0] = tv[1] = tv[2] = tv[3] = (f32x4){0.f, 0.f, 0.f, 0.f}; \
    } } } while (0)

// B(cn) straight into registers: lane reads exactly its own fragment,
// fully coalesced (64 lanes x 16B contiguous per ni). L2-resident.
#define LOAD_B(dst, cn) do { if ((cn) <= 8) { \
    _Pragma("unroll") \
    for (int ni = 0; ni < 8; ++ni) \
        dst[ni] = *reinterpret_cast<const bf16x8*>( \
            W1F + (size_t)(((cn) * 8 + ni) * 64 + lane) * 8); } } while (0)

#define CVT_STAGE(buf) do { u16x8 lo_, hi_; \
    _Pragma("unroll") \
    for (int j = 0; j < 4; ++j) { \
        lo_[j]     = f2bf(tv[0][j]); lo_[4 + j] = f2bf(tv[1][j]); \
        hi_[j]     = f2bf(tv[2][j]); hi_[4 + j] = f2bf(tv[3][j]); } \
    *reinterpret_cast<u16x8*>(&xs[(buf)][sm][sh * 16 + 0]) = lo_; \
    *reinterpret_cast<u16x8*>(&xs[(buf)][sm][sh * 16 + 8]) = hi_; } while (0)

#define MFMA_C(c, CUR) do { bf16x8 af0_, af1_; \
    af0_ = *reinterpret_cast<const bf16x8*>(&xs[(c) & 1][wm + fr][fq * 8]); \
    af1_ = *reinterpret_cast<const bf16x8*>(&xs[(c) & 1][wm + 16 + fr][fq * 8]); \
    _Pragma("unroll") \
    for (int ni = 0; ni < 8; ++ni) { \
        acc[0][ni] = __builtin_amdgcn_mfma_f32_16x16x32_bf16(af0_, CUR[ni], acc[0][ni], 0, 0, 0); \
        acc[1][ni] = __builtin_amdgcn_mfma_f32_16x16x32_bf16(af1_, CUR[ni], acc[1][ni], 0, 0, 0); } } while (0)

    // phase c: [issue B(c+1) -> NXT regs (ages a full phase)]
    //          [cvt tv=gather(c+1) -> xs[(c+1)&1]]  (compiler-counted vmcnt)
    //          [issue gather(c+2) -> tv]
    //          [MFMA chunk c from xs[c&1] + CUR regs]
#define PH(c, CUR, NXT) do { \
    LOAD_B(NXT, (c) + 1); \
    CVT_STAGE(((c) + 1) & 1); \
    GATHER((c) + 2); \
    MFMA_C(c, CUR); } while (0)

    // ---- prologue (per-wave, no barriers) ----
    GATHER(0);
    LOAD_B(bwA, 0);
    CVT_STAGE(0);      // waits gathers(0); B(0) loads keep flying
    GATHER(1);

    // ---- free-running pipeline, fully static buffer assignment ----
    PH(0, bwA, bwB);
    PH(1, bwB, bwA);
    PH(2, bwA, bwB);
    PH(3, bwB, bwA);
    PH(4, bwA, bwB);
    PH(5, bwB, bwA);
    PH(6, bwA, bwB);
    PH(7, bwB, bwA);   // loads B(8)->bwA; GATHER(9) no-op; cvt chunk 8 -> xs[0]
    MFMA_C(8, bwA);

    // ---------- epilogue: relu(+b1), @W2, pair-mean, +b2 ----------
    float b1v[8], w2a[8], w2b[8];
    #pragma unroll
    for (int ni = 0; ni < 8; ++ni) {
        int n = ni * 16 + fr;
        b1v[ni] = b1[n];
        w2a[ni] = W2[2 * n + 0];
        w2b[ni] = W2[2 * n + 1];
    }
    const float b20 = b2[0], b21 = b2[1];

    #pragma unroll
    for (int mi = 0; mi < 2; ++mi) {
        #pragma unroll
        for (int j = 0; j < 2; ++j) {
            // C/D rows fq*4 + 2j and fq*4 + 2j+1 form one output pair
            float s0 = 0.f, s1 = 0.f;
            #pragma unroll
            for (int ni = 0; ni < 8; ++ni) {
                float y0 = fmaxf(acc[mi][ni][2 * j]     + b1v[ni], 0.f);
                float y1 = fmaxf(acc[mi][ni][2 * j + 1] + b1v[ni], 0.f);
                float ys = y0 + y1;
                s0 = fmaf(ys, w2a[ni], s0);
                s1 = fmaf(ys, w2b[ni], s1);
            }
            #pragma unroll
            for (int off = 8; off >= 1; off >>= 1) {
                s0 += __shfl_xor(s0, off);
                s1 += __shfl_xor(s1, off);
            }
            if (fr == 0) {
                int mg = e0 + wm + mi * 16 + fq * 4 + 2 * j;   // even edge row
                size_t oi = ((size_t)b * (EA_E / 2) + (mg >> 1)) * 2;
                out[oi + 0] = 0.5f * s0 + b20;
                out[oi + 1] = 0.5f * s1 + b21;
            }
        }
    }
}

extern "C" void kernel_launch(void* const* d_in, const int* in_sizes, int n_in,
                              void* d_out, int out_size, void* d_ws, size_t ws_size,
                              hipStream_t stream) {
    const float* h          = (const float*)d_in[0];
    const int*   edge_index = (const int*)d_in[1];
    const float* edge_attr  = (const float*)d_in[2];
    const int*   etype      = (const int*)d_in[3];
    const float* W1         = (const float*)d_in[4];
    const float* b1         = (const float*)d_in[5];
    const float* W2         = (const float*)d_in[6];
    const float* b2         = (const float*)d_in[7];
    float* out = (float*)d_out;

    unsigned short* W1F = (unsigned short*)d_ws;   // 72*64*8 ushorts = 73728 B

    prep_w1<<<72, 64, 0, stream>>>(W1, W1F);

    dim3 grid(EA_E / TILE_M, NB);   // 625 x 4
    actor_head_mfma<<<grid, THREADS, 0, stream>>>(
        h, edge_index, edge_attr, etype, W1F, b1, W2, b2, out);
}

// Round 13
// 64.605 us; speedup vs baseline: 1.2355x; 1.2355x over previous
//
#include <hip/hip_runtime.h>
#include <hip/hip_bf16.h>

#define NB 4
#define N_NODES 100000
#define E_EDGES 160000
#define EA_E 80000
#define HID 128
#define ED 16

#define TILE_M 128
#define THREADS 256

typedef __attribute__((ext_vector_type(8))) short bf16x8;
typedef __attribute__((ext_vector_type(4))) float f32x4;
typedef __attribute__((ext_vector_type(8))) unsigned short u16x8;

__device__ __forceinline__ unsigned short f2bf(float f) {
    union { __hip_bfloat16 b; unsigned short u; } v;
    v.b = __float2bfloat16(f);   // RTNE
    return v.u;
}

__device__ __forceinline__ bf16x8 cvt8(f32x4 a, f32x4 c) {
    bf16x8 r;
    r[0] = (short)f2bf(a[0]); r[1] = (short)f2bf(a[1]);
    r[2] = (short)f2bf(a[2]); r[3] = (short)f2bf(a[3]);
    r[4] = (short)f2bf(c[0]); r[5] = (short)f2bf(c[1]);
    r[6] = (short)f2bf(c[2]); r[7] = (short)f2bf(c[3]);
    return r;
}

__device__ __forceinline__ void gll16(const void* g, void* l) {
    __builtin_amdgcn_global_load_lds(
        (const __attribute__((address_space(1))) unsigned int*)g,
        (__attribute__((address_space(3))) unsigned int*)l, 16, 0, 0);
}

// ---- pre-kernel: W1 (fp32 [272][128]) -> bf16 fragments in d_ws ----
// W1F[((c*8 + ni)*64 + lane)*8 + j]; n = ni*16 + (lane&15), k = c*32 + (lane>>4)*8 + j
__global__ void prep_w1(const float* __restrict__ W1, unsigned short* __restrict__ W1F) {
    const int cb   = blockIdx.x;      // 0..71 = c*8 + ni
    const int c    = cb >> 3;
    const int ni   = cb & 7;
    const int lane = threadIdx.x;     // 0..63
    const int fr   = lane & 15;
    const int fq   = lane >> 4;
    const int n    = ni * 16 + fr;
    u16x8 v;
    #pragma unroll
    for (int j = 0; j < 8; ++j) {
        int k = c * 32 + fq * 8 + j;
        float f = (k < 272) ? W1[(size_t)k * HID + n] : 0.f;
        v[j] = f2bf(f);
    }
    *reinterpret_cast<u16x8*>(W1F + ((size_t)(cb * 64 + lane)) * 8) = v;
}

__global__ __launch_bounds__(THREADS, 3) void actor_head_mfma(
    const float* __restrict__ h,            // [B][N][128]
    const int*   __restrict__ edge_index,   // [2][E]
    const float* __restrict__ edge_attr,    // [B][E][16]
    const int*   __restrict__ etype,        // [EA]
    const unsigned short* __restrict__ W1F, // bf16 fragment-ordered W1
    const float* __restrict__ b1,           // [128]
    const float* __restrict__ W2,           // [128][2]
    const float* __restrict__ b2,           // [2]
    float*       __restrict__ out)          // [B][EA/2][2]
{
    // A-fragments are gathered PER-LANE straight into registers:
    // lane (fr,fq) owns rows wm+fr / wm+16+fr, k-slice fq*8..fq*8+7 —
    // the (fr,fq) partition tiles the 32x128 wave tile exactly once.
    // No xs LDS. B keeps R8's block-cooperative gll->bws skeleton.
    __shared__ unsigned short bws[2][4096];   // B chunk double buffer
    __shared__ int sel[3][TILE_M];

    const int b  = blockIdx.y;
    const int e0 = blockIdx.x * TILE_M;
    const int t  = threadIdx.x;

    if (t < TILE_M) {
        int ei = etype[e0 + t];
        sel[2][t] = ei;
        sel[0][t] = edge_index[ei];
        sel[1][t] = edge_index[E_EDGES + ei];
    }

    const int lane = t & 63;
    const int wid  = t >> 6;          // 0..3
    const int wm   = wid * 32;        // wave owns rows wm..wm+31, all 128 cols
    const int fr   = lane & 15;
    const int fq   = lane >> 4;

    f32x4 tvA[4], tvB[4];             // gather dbuf: chunk c lives in tv(c&1)
    f32x4 acc[2][8];
    #pragma unroll
    for (int i = 0; i < 2; ++i)
        #pragma unroll
        for (int j = 0; j < 8; ++j) acc[i][j] = (f32x4){0.f, 0.f, 0.f, 0.f};

    __syncthreads();   // sel visible

    const int r0 = wm + fr, r1 = wm + 16 + fr;
    const float* pr0 = h + ((size_t)b * N_NODES + sel[0][r0]) * HID;
    const float* pr1 = h + ((size_t)b * N_NODES + sel[0][r1]) * HID;
    const float* ps0 = h + ((size_t)b * N_NODES + sel[1][r0]) * HID;
    const float* ps1 = h + ((size_t)b * N_NODES + sel[1][r1]) * HID;
    const float* pe0 = edge_attr + ((size_t)b * E_EDGES + sel[2][r0]) * ED;
    const float* pe1 = edge_attr + ((size_t)b * E_EDGES + sel[2][r1]) * ED;

#define GATHER(TV, cn) do { if ((cn) <= 8) { \
    if ((cn) < 8) { \
        const float* q0 = (((cn) < 4) ? pr0 : ps0) + ((cn) & 3) * 32 + fq * 8; \
        const float* q1 = (((cn) < 4) ? pr1 : ps1) + ((cn) & 3) * 32 + fq * 8; \
        TV[0] = *reinterpret_cast<const f32x4*>(q0); \
        TV[1] = *reinterpret_cast<const f32x4*>(q0 + 4); \
        TV[2] = *reinterpret_cast<const f32x4*>(q1); \
        TV[3] = *reinterpret_cast<const f32x4*>(q1 + 4); \
    } else if (fq < 2) { \
        TV[0] = *reinterpret_cast<const f32x4*>(pe0 + fq * 8); \
        TV[1] = *reinterpret_cast<const f32x4*>(pe0 + fq * 8 + 4); \
        TV[2] = *reinterpret_cast<const f32x4*>(pe1 + fq * 8); \
        TV[3] = *reinterpret_cast<const f32x4*>(pe1 + fq * 8 + 4); \
    } else { \
        TV[0] = TV[1] = TV[2] = TV[3] = (f32x4){0.f, 0.f, 0.f, 0.f}; \
    } } } while (0)

#define DMA_B(cn) do { if ((cn) <= 8) { \
    _Pragma("unroll") \
    for (int j2 = 0; j2 < 2; ++j2) \
        gll16(W1F + (size_t)(((cn) * 8 + j2 * 4 + wid) * 64 + lane) * 8, \
              &bws[(cn) & 1][(j2 * 4 + wid) * 512]); } } while (0)

#define MFMA_ACC(c, AF0, AF1) do { \
    _Pragma("unroll") \
    for (int ni = 0; ni < 8; ++ni) { \
        bf16x8 bw_ = *reinterpret_cast<const bf16x8*>(&bws[(c) & 1][ni * 512 + lane * 8]); \
        acc[0][ni] = __builtin_amdgcn_mfma_f32_16x16x32_bf16(AF0, bw_, acc[0][ni], 0, 0, 0); \
        acc[1][ni] = __builtin_amdgcn_mfma_f32_16x16x32_bf16(AF1, bw_, acc[1][ni], 0, 0, 0); } } while (0)

    // phase c: [2 glls B(c+1) — issued FIRST, oldest in queue]
    //          [cvt TV(chunk c) -> af (reads OLD TV values, then)]
    //          [GATHER(c+2) -> same TV (register rename; ages ~2 phases)]
    //          [16 MFMA chunk c] [vmcnt(VMN) retires glls only] [raw barrier]
#define PH(c, TV, VMN) do { \
    DMA_B((c) + 1); \
    __builtin_amdgcn_sched_barrier(0); \
    bf16x8 af0_ = cvt8(TV[0], TV[1]); \
    bf16x8 af1_ = cvt8(TV[2], TV[3]); \
    GATHER(TV, (c) + 2); \
    __builtin_amdgcn_sched_barrier(0); \
    MFMA_ACC(c, af0_, af1_); \
    __builtin_amdgcn_sched_barrier(0); \
    asm volatile("s_waitcnt vmcnt(" #VMN ")" ::: "memory"); \
    __builtin_amdgcn_sched_barrier(0); \
    __builtin_amdgcn_s_barrier(); } while (0)

    // ---- prologue ----
    GATHER(tvA, 0);                             // 4 loads (oldest)
    DMA_B(0);                                   // 2 glls
    __builtin_amdgcn_sched_barrier(0);
    GATHER(tvB, 1);                             // 4 loads (newest)
    __builtin_amdgcn_sched_barrier(0);
    asm volatile("s_waitcnt vmcnt(4)" ::: "memory");   // retire G0+L0; G1 flies
    __builtin_amdgcn_sched_barrier(0);
    __builtin_amdgcn_s_barrier();               // bws[0] ready

    PH(0, tvA, 4);
    PH(1, tvB, 4);
    PH(2, tvA, 4);
    PH(3, tvB, 4);
    PH(4, tvA, 4);
    PH(5, tvB, 4);
    PH(6, tvA, 4);     // GATHER(8) real (edge_attr, exec-masked, 4 loads/wave)
    PH(7, tvB, 0);     // GATHER(9) no-op; drain G8+L8
    {
        bf16x8 af8a = cvt8(tvA[0], tvA[1]);
        bf16x8 af8b = cvt8(tvA[2], tvA[3]);
        MFMA_ACC(8, af8a, af8b);   // bws[0] finalized by phase-7 barrier
    }

    // ---------- epilogue: relu(+b1), @W2, pair-mean, +b2 ----------
    float b1v[8], w2a[8], w2b[8];
    #pragma unroll
    for (int ni = 0; ni < 8; ++ni) {
        int n = ni * 16 + fr;
        b1v[ni] = b1[n];
        w2a[ni] = W2[2 * n + 0];
        w2b[ni] = W2[2 * n + 1];
    }
    const float b20 = b2[0], b21 = b2[1];

    #pragma unroll
    for (int mi = 0; mi < 2; ++mi) {
        #pragma unroll
        for (int j = 0; j < 2; ++j) {
            // C/D rows fq*4 + 2j and fq*4 + 2j+1 form one output pair
            float s0 = 0.f, s1 = 0.f;
            #pragma unroll
            for (int ni = 0; ni < 8; ++ni) {
                float y0 = fmaxf(acc[mi][ni][2 * j]     + b1v[ni], 0.f);
                float y1 = fmaxf(acc[mi][ni][2 * j + 1] + b1v[ni], 0.f);
                float ys = y0 + y1;
                s0 = fmaf(ys, w2a[ni], s0);
                s1 = fmaf(ys, w2b[ni], s1);
            }
            #pragma unroll
            for (int off = 8; off >= 1; off >>= 1) {
                s0 += __shfl_xor(s0, off);
                s1 += __shfl_xor(s1, off);
            }
            if (fr == 0) {
                int mg = e0 + wm + mi * 16 + fq * 4 + 2 * j;   // even edge row
                size_t oi = ((size_t)b * (EA_E / 2) + (mg >> 1)) * 2;
                out[oi + 0] = 0.5f * s0 + b20;
                out[oi + 1] = 0.5f * s1 + b21;
            }
        }
    }
}

extern "C" void kernel_launch(void* const* d_in, const int* in_sizes, int n_in,
                              void* d_out, int out_size, void* d_ws, size_t ws_size,
                              hipStream_t stream) {
    const float* h          = (const float*)d_in[0];
    const int*   edge_index = (const int*)d_in[1];
    const float* edge_attr  = (const float*)d_in[2];
    const int*   etype      = (const int*)d_in[3];
    const float* W1         = (const float*)d_in[4];
    const float* b1         = (const float*)d_in[5];
    const float* W2         = (const float*)d_in[6];
    const float* b2         = (const float*)d_in[7];
    float* out = (float*)d_out;

    unsigned short* W1F = (unsigned short*)d_ws;   // 72*64*8 ushorts = 73728 B

    prep_w1<<<72, 64, 0, stream>>>(W1, W1F);

    dim3 grid(EA_E / TILE_M, NB);   // 625 x 4
    actor_head_mfma<<<grid, THREADS, 0, stream>>>(
        h, edge_index, edge_attr, etype, W1F, b1, W2, b2, out);
}

// Round 14
// 62.102 us; speedup vs baseline: 1.2853x; 1.0403x over previous
//
#include <hip/hip_runtime.h>
#include <hip/hip_bf16.h>

#define NB 4
#define N_NODES 100000
#define E_EDGES 160000
#define EA_E 80000
#define HID 128
#define ED 16

#define TILE_M 256
#define THREADS 512
#define XPAD 40   // xs row length in ushort (32 used) -> 80B stride

typedef __attribute__((ext_vector_type(8))) short bf16x8;
typedef __attribute__((ext_vector_type(4))) float f32x4;
typedef __attribute__((ext_vector_type(8))) unsigned short u16x8;

__device__ __forceinline__ unsigned short f2bf(float f) {
    union { __hip_bfloat16 b; unsigned short u; } v;
    v.b = __float2bfloat16(f);   // RTNE
    return v.u;
}

__device__ __forceinline__ void gll16(const void* g, void* l) {
    __builtin_amdgcn_global_load_lds(
        (const __attribute__((address_space(1))) unsigned int*)g,
        (__attribute__((address_space(3))) unsigned int*)l, 16, 0, 0);
}

// ---- pre-kernel: W1 (fp32 [272][128]) -> bf16 fragments in d_ws ----
// W1F[((c*8 + ni)*64 + lane)*8 + j]; n = ni*16 + (lane&15), k = c*32 + (lane>>4)*8 + j
__global__ void prep_w1(const float* __restrict__ W1, unsigned short* __restrict__ W1F) {
    const int cb   = blockIdx.x;      // 0..71 = c*8 + ni
    const int c    = cb >> 3;
    const int ni   = cb & 7;
    const int lane = threadIdx.x;     // 0..63
    const int fr   = lane & 15;
    const int fq   = lane >> 4;
    const int n    = ni * 16 + fr;
    u16x8 v;
    #pragma unroll
    for (int j = 0; j < 8; ++j) {
        int k = c * 32 + fq * 8 + j;
        float f = (k < 272) ? W1[(size_t)k * HID + n] : 0.f;
        v[j] = f2bf(f);
    }
    *reinterpret_cast<u16x8*>(W1F + ((size_t)(cb * 64 + lane)) * 8) = v;
}

__global__ __launch_bounds__(THREADS, 2) void actor_head_mfma(
    const float* __restrict__ h,            // [B][N][128]
    const int*   __restrict__ edge_index,   // [2][E]
    const float* __restrict__ edge_attr,    // [B][E][16]
    const int*   __restrict__ etype,        // [EA]
    const unsigned short* __restrict__ W1F, // bf16 fragment-ordered W1
    const float* __restrict__ b1,           // [128]
    const float* __restrict__ W2,           // [128][2]
    const float* __restrict__ b2,           // [2]
    float*       __restrict__ out)          // [B][EA/2][2]
{
    __shared__ unsigned short xs[2][TILE_M][XPAD]; // x tile double buffer (41 KB)
    __shared__ unsigned short bws[2][4096];        // B chunk double buffer (16 KB)
    __shared__ int sel[3][TILE_M];

    const int b  = blockIdx.y;
    const int e0 = blockIdx.x * TILE_M;
    const int t  = threadIdx.x;

    if (t < TILE_M) {
        int idx = e0 + t;
        if (idx >= EA_E) idx = EA_E - 1;   // tail clamp (stores guarded below)
        int ei = etype[idx];
        sel[2][t] = ei;
        sel[0][t] = edge_index[ei];
        sel[1][t] = edge_index[E_EDGES + ei];
    }

    const int lane = t & 63;
    const int wid  = t >> 6;          // 0..7
    const int wm   = wid * 32;        // wave owns rows wm..wm+31, all 128 cols
    const int fr   = lane & 15;
    const int fq   = lane >> 4;

    // staging roles: 2 threads per x row, 16 floats each
    const int sm = t >> 1;            // 0..255
    const int sh = t & 1;

    f32x4 tv[4];
    f32x4 acc[2][8];
    #pragma unroll
    for (int i = 0; i < 2; ++i)
        #pragma unroll
        for (int j = 0; j < 8; ++j) acc[i][j] = (f32x4){0.f, 0.f, 0.f, 0.f};

    __syncthreads();   // sel visible (full barrier ok, once)

    const float* hr = h + ((size_t)b * N_NODES + sel[0][sm]) * HID + sh * 16;
    const float* hs = h + ((size_t)b * N_NODES + sel[1][sm]) * HID + sh * 16;
    const float* ea = edge_attr + ((size_t)b * E_EDGES + sel[2][sm]) * ED;

#define GATHER(cn) do { if ((cn) <= 8) { \
    if ((cn) < 8) { \
        const float* q = (((cn) < 4) ? hr : hs) + ((cn) & 3) * 32; \
        tv[0] = *reinterpret_cast<const f32x4*>(q); \
        tv[1] = *reinterpret_cast<const f32x4*>(q + 4); \
        tv[2] = *reinterpret_cast<const f32x4*>(q + 8); \
        tv[3] = *reinterpret_cast<const f32x4*>(q + 12); \
    } else if (sh == 0) { \
        tv[0] = *reinterpret_cast<const f32x4*>(ea); \
        tv[1] = *reinterpret_cast<const f32x4*>(ea + 4); \
        tv[2] = *reinterpret_cast<const f32x4*>(ea + 8); \
        tv[3] = *reinterpret_cast<const f32x4*>(ea + 12); \
    } else { \
        tv[0] = tv[1] = tv[2] = tv[3] = (f32x4){0.f, 0.f, 0.f, 0.f}; \
    } } } while (0)

// 8 waves: wave wid stages B sub-block ni = wid -> exactly 1 gll per thread.
#define DMA_B(cn) do { if ((cn) <= 8) { \
    gll16(W1F + (size_t)(((cn) * 8 + wid) * 64 + lane) * 8, \
          &bws[(cn) & 1][wid * 512]); } } while (0)

#define CVT_STAGE(buf) do { u16x8 lo_, hi_; \
    _Pragma("unroll") \
    for (int j = 0; j < 4; ++j) { \
        lo_[j]     = f2bf(tv[0][j]); lo_[4 + j] = f2bf(tv[1][j]); \
        hi_[j]     = f2bf(tv[2][j]); hi_[4 + j] = f2bf(tv[3][j]); } \
    *reinterpret_cast<u16x8*>(&xs[(buf)][sm][sh * 16 + 0]) = lo_; \
    *reinterpret_cast<u16x8*>(&xs[(buf)][sm][sh * 16 + 8]) = hi_; } while (0)

#define MFMA_C(c) do { bf16x8 af0_, af1_; \
    af0_ = *reinterpret_cast<const bf16x8*>(&xs[(c) & 1][wm + fr][fq * 8]); \
    af1_ = *reinterpret_cast<const bf16x8*>(&xs[(c) & 1][wm + 16 + fr][fq * 8]); \
    _Pragma("unroll") \
    for (int ni = 0; ni < 8; ++ni) { \
        bf16x8 bw_ = *reinterpret_cast<const bf16x8*>(&bws[(c) & 1][ni * 512 + lane * 8]); \
        acc[0][ni] = __builtin_amdgcn_mfma_f32_16x16x32_bf16(af0_, bw_, acc[0][ni], 0, 0, 0); \
        acc[1][ni] = __builtin_amdgcn_mfma_f32_16x16x32_bf16(af1_, bw_, acc[1][ni], 0, 0, 0); } } while (0)

    // ---- prologue ----
    DMA_B(0);                                   // 1 gll, oldest
    __builtin_amdgcn_sched_barrier(0);
    GATHER(0);
    CVT_STAGE(0);                               // compiler-counted vmcnt (drains gll too)
    GATHER(1);                                  // survives the raw barrier below
    __builtin_amdgcn_sched_barrier(0);
    asm volatile("s_waitcnt vmcnt(4) lgkmcnt(0)" ::: "memory");
    __builtin_amdgcn_sched_barrier(0);
    __builtin_amdgcn_s_barrier();               // xs[0], bws[0] ready

    // ---- main loop: raw barriers, counted vmcnt (T3/T4) ----
    for (int c = 0; c < 8; ++c) {
        DMA_B(c + 1);                           // 1 gll first -> oldest this phase
        __builtin_amdgcn_sched_barrier(0);      // pin: nothing moves above the gll
        CVT_STAGE((c + 1) & 1);                 // consumes prev-phase gathers (counted wait)
        GATHER(c + 2);                          // 4 exec-masked loads/wave (phases 0..6)
        MFMA_C(c);
        __builtin_amdgcn_sched_barrier(0);
        if (c < 7) {
            // drain exactly the 1 gll (oldest, in-order retire);
            // the 4 gathers keep flying across the barrier.
            asm volatile("s_waitcnt vmcnt(4) lgkmcnt(0)" ::: "memory");
        } else {
            // phase 7: GATHER(9) is a no-op; only the gll is outstanding
            asm volatile("s_waitcnt vmcnt(0) lgkmcnt(0)" ::: "memory");
        }
        __builtin_amdgcn_sched_barrier(0);
        __builtin_amdgcn_s_barrier();
    }
    MFMA_C(8);                                  // bws[0]/xs[0] finalized by phase-7 barrier

    // ---------- epilogue: relu(+b1), @W2, pair-mean, +b2 ----------
    float b1v[8], w2a[8], w2b[8];
    #pragma unroll
    for (int ni = 0; ni < 8; ++ni) {
        int n = ni * 16 + fr;
        b1v[ni] = b1[n];
        w2a[ni] = W2[2 * n + 0];
        w2b[ni] = W2[2 * n + 1];
    }
    const float b20 = b2[0], b21 = b2[1];

    #pragma unroll
    for (int mi = 0; mi < 2; ++mi) {
        #pragma unroll
        for (int j = 0; j < 2; ++j) {
            // C/D rows fq*4 + 2j and fq*4 + 2j+1 form one output pair
            float s0 = 0.f, s1 = 0.f;
            #pragma unroll
            for (int ni = 0; ni < 8; ++ni) {
                float y0 = fmaxf(acc[mi][ni][2 * j]     + b1v[ni], 0.f);
                float y1 = fmaxf(acc[mi][ni][2 * j + 1] + b1v[ni], 0.f);
                float ys = y0 + y1;
                s0 = fmaf(ys, w2a[ni], s0);
                s1 = fmaf(ys, w2b[ni], s1);
            }
            #pragma unroll
            for (int off = 8; off >= 1; off >>= 1) {
                s0 += __shfl_xor(s0, off);
                s1 += __shfl_xor(s1, off);
            }
            if (fr == 0) {
                int mg = e0 + wm + mi * 16 + fq * 4 + 2 * j;   // even edge row
                if (mg < EA_E) {
                    size_t oi = ((size_t)b * (EA_E / 2) + (mg >> 1)) * 2;
                    out[oi + 0] = 0.5f * s0 + b20;
                    out[oi + 1] = 0.5f * s1 + b21;
                }
            }
        }
    }
}

extern "C" void kernel_launch(void* const* d_in, const int* in_sizes, int n_in,
                              void* d_out, int out_size, void* d_ws, size_t ws_size,
                              hipStream_t stream) {
    const float* h          = (const float*)d_in[0];
    const int*   edge_index = (const int*)d_in[1];
    const float* edge_attr  = (const float*)d_in[2];
    const int*   etype      = (const int*)d_in[3];
    const float* W1         = (const float*)d_in[4];
    const float* b1         = (const float*)d_in[5];
    const float* W2         = (const float*)d_in[6];
    const float* b2         = (const float*)d_in[7];
    float* out = (float*)d_out;

    unsigned short* W1F = (unsigned short*)d_ws;   // 72*64*8 ushorts = 73728 B

    prep_w1<<<72, 64, 0, stream>>>(W1, W1F);

    dim3 grid((EA_E + TILE_M - 1) / TILE_M, NB);   // 313 x 4
    actor_head_mfma<<<grid, THREADS, 0, stream>>>(
        h, edge_index, edge_attr, etype, W1F, b1, W2, b2, out);
}

// Round 15
// 61.238 us; speedup vs baseline: 1.3035x; 1.0141x over previous
//
#include <hip/hip_runtime.h>
#include <hip/hip_bf16.h>

#define NB 4
#define N_NODES 100000
#define E_EDGES 160000
#define EA_E 80000
#define HID 128
#define ED 16

#define TILE_M 128
#define THREADS 256
#define XPAD 40   // xs row length in ushort (32 used) -> 80B stride

typedef __attribute__((ext_vector_type(8))) short bf16x8;
typedef __attribute__((ext_vector_type(4))) float f32x4;
typedef __attribute__((ext_vector_type(8))) unsigned short u16x8;

__device__ __forceinline__ unsigned short f2bf(float f) {
    union { __hip_bfloat16 b; unsigned short u; } v;
    v.b = __float2bfloat16(f);   // RTNE
    return v.u;
}

__device__ __forceinline__ void gll16(const void* g, void* l) {
    __builtin_amdgcn_global_load_lds(
        (const __attribute__((address_space(1))) unsigned int*)g,
        (__attribute__((address_space(3))) unsigned int*)l, 16, 0, 0);
}

// ---- pre-kernel: W1 (fp32 [272][128]) -> bf16 fragments in d_ws ----
// W1F[((c*8 + ni)*64 + lane)*8 + j]; n = ni*16 + (lane&15), k = c*32 + (lane>>4)*8 + j
__global__ void prep_w1(const float* __restrict__ W1, unsigned short* __restrict__ W1F) {
    const int cb   = blockIdx.x;      // 0..71 = c*8 + ni
    const int c    = cb >> 3;
    const int ni   = cb & 7;
    const int lane = threadIdx.x;     // 0..63
    const int fr   = lane & 15;
    const int fq   = lane >> 4;
    const int n    = ni * 16 + fr;
    u16x8 v;
    #pragma unroll
    for (int j = 0; j < 8; ++j) {
        int k = c * 32 + fq * 8 + j;
        float f = (k < 272) ? W1[(size_t)k * HID + n] : 0.f;
        v[j] = f2bf(f);
    }
    *reinterpret_cast<u16x8*>(W1F + ((size_t)(cb * 64 + lane)) * 8) = v;
}

__global__ __launch_bounds__(THREADS, 3) void actor_head_mfma(
    const float* __restrict__ h,            // [B][N][128]
    const int*   __restrict__ edge_index,   // [2][E]
    const float* __restrict__ edge_attr,    // [B][E][16]
    const int*   __restrict__ etype,        // [EA]
    const unsigned short* __restrict__ W1F, // bf16 fragment-ordered W1
    const float* __restrict__ b1,           // [128]
    const float* __restrict__ W2,           // [128][2]
    const float* __restrict__ b2,           // [2]
    float*       __restrict__ out)          // [B][EA/2][2]
{
    __shared__ unsigned short xs[2][TILE_M][XPAD]; // x tile double buffer
    __shared__ unsigned short bws[3][4096];        // B chunk TRIPLE buffer (depth-2 glls)
    __shared__ int sel[3][TILE_M];

    const int b  = blockIdx.y;
    const int e0 = blockIdx.x * TILE_M;
    const int t  = threadIdx.x;

    if (t < TILE_M) {
        int ei = etype[e0 + t];
        sel[2][t] = ei;
        sel[0][t] = edge_index[ei];
        sel[1][t] = edge_index[E_EDGES + ei];
    }

    const int lane = t & 63;
    const int wid  = t >> 6;          // 0..3
    const int wm   = wid * 32;        // wave owns rows wm..wm+31, all 128 cols
    const int fr   = lane & 15;
    const int fq   = lane >> 4;

    // staging roles: 2 threads per x row, 16 floats each
    const int sm = t >> 1;
    const int sh = t & 1;

    f32x4 tvA[4], tvB[4];             // chunk k's gather data lives in tv(k&1)
    f32x4 acc[2][8];
    #pragma unroll
    for (int i = 0; i < 2; ++i)
        #pragma unroll
        for (int j = 0; j < 8; ++j) acc[i][j] = (f32x4){0.f, 0.f, 0.f, 0.f};

    __syncthreads();   // sel visible (full barrier ok, once)

    const float* hr = h + ((size_t)b * N_NODES + sel[0][sm]) * HID + sh * 16;
    const float* hs = h + ((size_t)b * N_NODES + sel[1][sm]) * HID + sh * 16;
    const float* ea = edge_attr + ((size_t)b * E_EDGES + sel[2][sm]) * ED;

#define GATHER(TV, cn) do { if ((cn) <= 8) { \
    if ((cn) < 8) { \
        const float* q = (((cn) < 4) ? hr : hs) + ((cn) & 3) * 32; \
        TV[0] = *reinterpret_cast<const f32x4*>(q); \
        TV[1] = *reinterpret_cast<const f32x4*>(q + 4); \
        TV[2] = *reinterpret_cast<const f32x4*>(q + 8); \
        TV[3] = *reinterpret_cast<const f32x4*>(q + 12); \
    } else if (sh == 0) { \
        TV[0] = *reinterpret_cast<const f32x4*>(ea); \
        TV[1] = *reinterpret_cast<const f32x4*>(ea + 4); \
        TV[2] = *reinterpret_cast<const f32x4*>(ea + 8); \
        TV[3] = *reinterpret_cast<const f32x4*>(ea + 12); \
    } else { \
        TV[0] = TV[1] = TV[2] = TV[3] = (f32x4){0.f, 0.f, 0.f, 0.f}; \
    } } } while (0)

#define DMA_B(cn) do { if ((cn) <= 8) { \
    _Pragma("unroll") \
    for (int j2 = 0; j2 < 2; ++j2) \
        gll16(W1F + (size_t)(((cn) * 8 + j2 * 4 + wid) * 64 + lane) * 8, \
              &bws[(cn) % 3][(j2 * 4 + wid) * 512]); } } while (0)

#define CVT_STAGE(TV, buf) do { u16x8 lo_, hi_; \
    _Pragma("unroll") \
    for (int j = 0; j < 4; ++j) { \
        lo_[j]     = f2bf(TV[0][j]); lo_[4 + j] = f2bf(TV[1][j]); \
        hi_[j]     = f2bf(TV[2][j]); hi_[4 + j] = f2bf(TV[3][j]); } \
    *reinterpret_cast<u16x8*>(&xs[(buf)][sm][sh * 16 + 0]) = lo_; \
    *reinterpret_cast<u16x8*>(&xs[(buf)][sm][sh * 16 + 8]) = hi_; } while (0)

#define MFMA_C(c) do { bf16x8 af0_, af1_; \
    af0_ = *reinterpret_cast<const bf16x8*>(&xs[(c) & 1][wm + fr][fq * 8]); \
    af1_ = *reinterpret_cast<const bf16x8*>(&xs[(c) & 1][wm + 16 + fr][fq * 8]); \
    _Pragma("unroll") \
    for (int ni = 0; ni < 8; ++ni) { \
        bf16x8 bw_ = *reinterpret_cast<const bf16x8*>(&bws[(c) % 3][ni * 512 + lane * 8]); \
        acc[0][ni] = __builtin_amdgcn_mfma_f32_16x16x32_bf16(af0_, bw_, acc[0][ni], 0, 0, 0); \
        acc[1][ni] = __builtin_amdgcn_mfma_f32_16x16x32_bf16(af1_, bw_, acc[1][ni], 0, 0, 0); } } while (0)

    // phase c: [2 glls B(c+2) -> bws[(c+2)%3] (ages TWO phase bodies)]
    //          [cvt TV = chunk c+1 -> xs[(c+1)&1]]  (counted wait on G(c+1), aged ~2.3 phases)
    //          [GATHER(c+3) -> same-parity TV (after the cvt read)]
    //          [16 MFMA chunk c] [vmcnt(VMN) retires exactly L(c+1)] [raw barrier]
    // steady queue at drain: L(c+1)2, G(c+2)4, L(c+2)2, G(c+3)4 = 12 -> vmcnt(10)
#define PH(c, TV, VMN) do { \
    DMA_B((c) + 2); \
    __builtin_amdgcn_sched_barrier(0); \
    CVT_STAGE(TV, ((c) + 1) & 1); \
    GATHER(TV, (c) + 3); \
    __builtin_amdgcn_sched_barrier(0); \
    MFMA_C(c); \
    __builtin_amdgcn_sched_barrier(0); \
    asm volatile("s_waitcnt vmcnt(" #VMN ") lgkmcnt(0)" ::: "memory"); \
    __builtin_amdgcn_sched_barrier(0); \
    __builtin_amdgcn_s_barrier(); } while (0)

    // ---- prologue: establish G(k)-before-L(k) order, 12-deep queue ----
    GATHER(tvA, 0);                             // G0
    DMA_B(0);                                   // L0
    GATHER(tvB, 1);                             // G1
    DMA_B(1);                                   // L1
    __builtin_amdgcn_sched_barrier(0);
    CVT_STAGE(tvA, 0);                          // waits G0 (retires G0, leaves L0,G1,L1)
    GATHER(tvA, 2);                             // G2 (after cvt read of tvA)
    __builtin_amdgcn_sched_barrier(0);
    asm volatile("s_waitcnt vmcnt(10) lgkmcnt(0)" ::: "memory");  // retire L0
    __builtin_amdgcn_sched_barrier(0);
    __builtin_amdgcn_s_barrier();               // xs[0], bws[0] ready

    PH(0, tvB, 10);
    PH(1, tvA, 10);
    PH(2, tvB, 10);
    PH(3, tvA, 10);
    PH(4, tvB, 10);
    PH(5, tvA, 10);
    PH(6, tvB, 6);     // L(8) issued; G(9) no-op; drain L(7)
    PH(7, tvA, 0);     // L(9)/G(10) no-ops; cvt(8); drain L(8)
    MFMA_C(8);         // xs[0], bws[2]; finalized by phase-7 barrier

    // ---------- epilogue: relu(+b1), @W2, pair-mean, +b2 ----------
    float b1v[8], w2a[8], w2b[8];
    #pragma unroll
    for (int ni = 0; ni < 8; ++ni) {
        int n = ni * 16 + fr;
        b1v[ni] = b1[n];
        w2a[ni] = W2[2 * n + 0];
        w2b[ni] = W2[2 * n + 1];
    }
    const float b20 = b2[0], b21 = b2[1];

    #pragma unroll
    for (int mi = 0; mi < 2; ++mi) {
        #pragma unroll
        for (int j = 0; j < 2; ++j) {
            // C/D rows fq*4 + 2j and fq*4 + 2j+1 form one output pair
            float s0 = 0.f, s1 = 0.f;
            #pragma unroll
            for (int ni = 0; ni < 8; ++ni) {
                float y0 = fmaxf(acc[mi][ni][2 * j]     + b1v[ni], 0.f);
                float y1 = fmaxf(acc[mi][ni][2 * j + 1] + b1v[ni], 0.f);
                float ys = y0 + y1;
                s0 = fmaf(ys, w2a[ni], s0);
                s1 = fmaf(ys, w2b[ni], s1);
            }
            #pragma unroll
            for (int off = 8; off >= 1; off >>= 1) {
                s0 += __shfl_xor(s0, off);
                s1 += __shfl_xor(s1, off);
            }
            if (fr == 0) {
                int mg = e0 + wm + mi * 16 + fq * 4 + 2 * j;   // even edge row
                size_t oi = ((size_t)b * (EA_E / 2) + (mg >> 1)) * 2;
                out[oi + 0] = 0.5f * s0 + b20;
                out[oi + 1] = 0.5f * s1 + b21;
            }
        }
    }
}

extern "C" void kernel_launch(void* const* d_in, const int* in_sizes, int n_in,
                              void* d_out, int out_size, void* d_ws, size_t ws_size,
                              hipStream_t stream) {
    const float* h          = (const float*)d_in[0];
    const int*   edge_index = (const int*)d_in[1];
    const float* edge_attr  = (const float*)d_in[2];
    const int*   etype      = (const int*)d_in[3];
    const float* W1         = (const float*)d_in[4];
    const float* b1         = (const float*)d_in[5];
    const float* W2         = (const float*)d_in[6];
    const float* b2         = (const float*)d_in[7];
    float* out = (float*)d_out;

    unsigned short* W1F = (unsigned short*)d_ws;   // 72*64*8 ushorts = 73728 B

    prep_w1<<<72, 64, 0, stream>>>(W1, W1F);

    dim3 grid(EA_E / TILE_M, NB);   // 625 x 4
    actor_head_mfma<<<grid, THREADS, 0, stream>>>(
        h, edge_index, edge_attr, etype, W1F, b1, W2, b2, out);
}